// Round 2
// baseline (124782.202 us; speedup 1.0000x reference)
//
#include <hip/hip_runtime.h>

// ============================================================================
// GRU encode (1024 steps) + autoregressive decode (256 steps), B=128, I=256,
// H=1024, fp32 throughout (CDNA4 has no fp32 MFMA; this is the vector-ALU
// baseline — bf16x3 MFMA planned next round).
//
// Design:
//  - ONE persistent cooperative kernel: 256 WGs x 512 threads, 1 WG/CU
//    (LDS 132KB forces 1/CU). 1280 sequential steps inside the kernel.
//  - Batches split into 2 independent groups of 64; each group = 128 WGs with
//    its own spread-line atomic barrier (8 lines x 16 arrivals) -> no
//    grid-wide sync, groups drift freely.
//  - Barrier uses RELAXED spin + single acquire fence on exit: an agent-scope
//    acquire *inside* the spin would issue an L1/L2 invalidate per iteration
//    on gfx950 (non-coherent XCD L2s), destroying weight cache residency.
//  - Per WG: 8 hidden units (24 gate rows, r/z/n adjacent), all 64 batches of
//    its group. Thread = (batch, 6 rows, k-half). Separate x-part / h-part
//    accumulators (n-gate needs i_n and h_n apart).
//  - Weights stream from global at wave-uniform (readfirstlane-derived)
//    addresses -> scalar/L1 broadcast path, keeping the LDS pipe for X only.
//    Per-XCD W working set ~2-4MB -> mostly L2 resident.
//  - X staged in LDS as float4 slots, row*33+slot padding -> minimal 8-rotation
//    bank pattern for ds_read_b128; double-buffered pairs, 1 sync per pair.
// ============================================================================

#define I_SZ 256
#define H_SZ 1024
#define B_SZ 128
#define S_SZ 1024
#define T_SZ 256

#define NWG 256
#define NTHR 512
#define SLOTS 33                      // float4 slots per 128-float row (32+1 pad)
#define BUF_F4 (64 * SLOTS)           // 2112 float4 per chunk buffer
#define SMEM_BYTES (4 * BUF_F4 * 16)  // 135168 bytes (4 chunk buffers)

#define WS_H_OFF 4096

__device__ __forceinline__ float sigmoidf_(float v) {
  return 1.0f / (1.0f + __expf(-v));
}
__device__ __forceinline__ float tanhf_(float v) {
  // 2*sigmoid(2x)-1 : safe at both extremes (expf overflow -> +-1 exactly)
  return 2.0f / (1.0f + __expf(-2.0f * v)) - 1.0f;
}

__global__ void __launch_bounds__(NTHR, 2)
gru_ar_kernel(const float* __restrict__ x, const float* __restrict__ Wih,
              const float* __restrict__ Whh, const float* __restrict__ bih,
              const float* __restrict__ bhh, const float* __restrict__ Wlin,
              const float* __restrict__ blin, float* __restrict__ out,
              float* __restrict__ h0, float* __restrict__ h1,
              float* __restrict__ ybuf, unsigned* __restrict__ ctrs) {
  extern __shared__ float4 smem4[];
  const int tid = threadIdx.x;
  const int wg  = blockIdx.x;
  const int g   = wg >> 7;    // batch group 0/1
  const int wgl = wg & 127;   // WG index within group
  const int u0  = wgl * 8;    // this WG's 8 hidden units
  const int bg0 = g * 64;     // group's first batch
  const int b   = tid & 63;   // thread's batch (lane)
  const int rg  = __builtin_amdgcn_readfirstlane((tid >> 6) & 3);  // row group
  const int kh  = __builtin_amdgcn_readfirstlane(tid >> 8);        // k half
  const int wv  = __builtin_amdgcn_readfirstlane(tid >> 6);        // wave id

  // This thread's 6 gate rows: units u0+rg*2, u0+rg*2+1, gates (r,z,n) each.
  // PyTorch row layout: [0:H)=r, [H:2H)=z, [2H:3H)=n.
  int grow[6];
  float bi[6], bh_[6];
#pragma unroll
  for (int jj = 0; jj < 6; ++jj) {
    const int jloc = rg * 6 + jj;
    grow[jj] = (jloc % 3) * H_SZ + u0 + jloc / 3;
    bi[jj]   = bih[grow[jj]];
    bh_[jj]  = bhh[grow[jj]];
  }

  unsigned* myline = ctrs + g * 256 + (wgl & 7) * 32;  // 128B-spaced lines
  float* hc = h0;
  float* hn = h1;
  int phase = 0;

  // ---- group-local barrier ----
  // release: one __threadfence (agent) + RELAXED add.
  // acquire: RELAXED spin (no per-iteration cache invalidate!) then one
  // __threadfence; wave0's buffer_inv covers the CU's L1, __syncthreads
  // orders the other waves' subsequent loads behind it.
  auto group_barrier = [&]() {
    ++phase;
    __syncthreads();
    if (tid == 0) {
      __threadfence();
      __hip_atomic_fetch_add(myline, 1u, __ATOMIC_RELAXED,
                             __HIP_MEMORY_SCOPE_AGENT);
    }
    if (tid < 8) {
      unsigned* ln = ctrs + g * 256 + tid * 32;
      const unsigned tgt = (unsigned)phase * 16u;  // 16 WGs per line
      while (__hip_atomic_load(ln, __ATOMIC_RELAXED,
                               __HIP_MEMORY_SCOPE_AGENT) < tgt)
        __builtin_amdgcn_s_sleep(2);
      __threadfence();
    }
    __syncthreads();
  };

  // ---- one FMA chunk: 6 rows x 128 k, X from LDS, W uniform from global ----
  auto do_chunk = [&](float (&ac)[6], const float4* __restrict__ xb,
                      const float* __restrict__ wbase, long wstride, int kc0) {
    const float* wp[6];
#pragma unroll
    for (int jj = 0; jj < 6; ++jj)
      wp[jj] = wbase + (long)grow[jj] * wstride + kc0;
#pragma unroll 8
    for (int k4 = 0; k4 < 32; ++k4) {
      const float4 xv = xb[k4];
#pragma unroll
      for (int jj = 0; jj < 6; ++jj) {
        const float4 wv4 = *(const float4*)(wp[jj] + 4 * k4);
        ac[jj] = fmaf(xv.x, wv4.x, ac[jj]);
        ac[jj] = fmaf(xv.y, wv4.y, ac[jj]);
        ac[jj] = fmaf(xv.z, wv4.z, ac[jj]);
        ac[jj] = fmaf(xv.w, wv4.w, ac[jj]);
      }
    }
  };

  // ---- one GRU gate step: X = concat(srcA row [0:256), h [256:1280)) ----
  auto gates_step = [&](const float* srcA, long strA) {
    float accA[6], accB[6];
#pragma unroll
    for (int i = 0; i < 6; ++i) { accA[i] = 0.f; accB[i] = 0.f; }
    const float* hg = hc + (long)bg0 * H_SZ;

    const int srow = tid >> 3;       // staging row 0..63
    const int s0   = (tid & 7) * 4;  // staging f4 slot base
    float4 pf[8];

    auto stage_issue = [&](int pair) {
#pragma unroll
      for (int h = 0; h < 2; ++h) {
        const int kc = h * 640 + pair * 128;  // chunk never straddles k=256
        const float* src; long rs;
        if (kc < 256) { src = srcA + kc;         rs = strA; }
        else          { src = hg + (kc - 256);   rs = H_SZ; }
        const float* p = src + (long)srow * rs + 4 * s0;
#pragma unroll
        for (int i = 0; i < 4; ++i)
          pf[h * 4 + i] = *(const float4*)(p + 4 * i);
      }
    };
    auto stage_write = [&](int pair) {
#pragma unroll
      for (int h = 0; h < 2; ++h) {
        float4* bufb = smem4 + (h * 2 + (pair & 1)) * BUF_F4;
#pragma unroll
        for (int i = 0; i < 4; ++i)
          bufb[srow * SLOTS + s0 + i] = pf[h * 4 + i];
      }
    };

    stage_issue(0);
    stage_write(0);
    __syncthreads();

    for (int p = 0; p < 5; ++p) {
      if (p < 4) stage_issue(p + 1);
      {
        const int kc = kh * 640 + p * 128;
        const float4* xb =
            smem4 + (kh * 2 + (p & 1)) * BUF_F4 + b * SLOTS;
        if (kc < 256) do_chunk(accA, xb, Wih, I_SZ, kc);
        else          do_chunk(accB, xb, Whh, H_SZ, kc - 256);
      }
      if (p < 4) stage_write(p + 1);
      __syncthreads();
    }

    // fold k-half 1's h-part partials into k-half 0
    float* red = (float*)smem4;  // reuse buffer 0 region (sync'd above)
    if (kh == 1) {
#pragma unroll
      for (int jj = 0; jj < 6; ++jj) red[(tid & 255) * 6 + jj] = accB[jj];
    }
    __syncthreads();
    if (kh == 0) {
#pragma unroll
      for (int jj = 0; jj < 6; ++jj) accB[jj] += red[tid * 6 + jj];
#pragma unroll
      for (int ui = 0; ui < 2; ++ui) {
        const int j0 = ui * 3;
        const float rr = sigmoidf_(accA[j0]     + accB[j0]     + bi[j0]     + bh_[j0]);
        const float zz = sigmoidf_(accA[j0 + 1] + accB[j0 + 1] + bi[j0 + 1] + bh_[j0 + 1]);
        const float nn = tanhf_(accA[j0 + 2] + bi[j0 + 2] +
                                rr * (accB[j0 + 2] + bh_[j0 + 2]));
        const int u = u0 + rg * 2 + ui;
        const long hidx = (long)(bg0 + b) * H_SZ + u;
        const float hp = hc[hidx];
        hn[hidx] = (1.f - zz) * nn + zz * hp;
      }
    }
  };

  // ---- y = h @ Wlin^T + blin  (2 output cols per WG, 4-way K split) ----
  auto lin_step = [&](bool emit, int tstep) {
    const float* hg = hc + (long)bg0 * H_SZ;
    const int o0 = wgl * 2;
    const int o_loc = wv & 1;
    const int sec   = wv >> 1;  // k section 0..3 (256 k each)
    float accl = 0.f;
    for (int r = 0; r < 2; ++r) {
#pragma unroll
      for (int i = 0; i < 16; ++i) {
        const int f = tid + i * 512;                // 8192 f4 = 4 chunks
        const int bq = f >> 11, rem = f & 2047;
        const int row = rem >> 5, slot = rem & 31;
        const int k = bq * 256 + r * 128 + slot * 4;
        smem4[bq * BUF_F4 + row * SLOTS + slot] =
            *(const float4*)(hg + (long)row * H_SZ + k);
      }
      __syncthreads();
      const float4* xb = smem4 + sec * BUF_F4 + b * SLOTS;
      const float* wl = Wlin + (long)(o0 + o_loc) * H_SZ + sec * 256 + r * 128;
#pragma unroll 8
      for (int k4 = 0; k4 < 32; ++k4) {
        const float4 xv = xb[k4];
        const float4 wv4 = *(const float4*)(wl + 4 * k4);
        accl = fmaf(xv.x, wv4.x, accl);
        accl = fmaf(xv.y, wv4.y, accl);
        accl = fmaf(xv.z, wv4.z, accl);
        accl = fmaf(xv.w, wv4.w, accl);
      }
      __syncthreads();
    }
    float* red = (float*)smem4;
    red[(o_loc * 64 + b) * 4 + sec] = accl;
    __syncthreads();
    if (tid < 128) {
      const int bb = tid & 63, ol = tid >> 6;
      const float y = red[tid * 4 + 0] + red[tid * 4 + 1] +
                      red[tid * 4 + 2] + red[tid * 4 + 3] + blin[o0 + ol];
      ybuf[(long)(bg0 + bb) * I_SZ + o0 + ol] = y;
      if (emit)
        out[((long)(bg0 + bb) * T_SZ + tstep) * I_SZ + o0 + ol] = y;
    }
  };

  // ======================= encode =======================
  for (int t = 0; t < S_SZ; ++t) {
    gates_step(x + ((long)bg0 * S_SZ + t) * I_SZ, (long)S_SZ * I_SZ);
    group_barrier();
    float* tmp = hc; hc = hn; hn = tmp;
  }
  // ======================= y0 ===========================
  lin_step(false, 0);
  group_barrier();
  // ======================= decode =======================
  for (int t = 0; t < T_SZ; ++t) {
    gates_step(ybuf + (long)bg0 * I_SZ, I_SZ);
    group_barrier();
    float* tmp = hc; hc = hn; hn = tmp;
    lin_step(true, t);
    group_barrier();
  }
}

extern "C" void kernel_launch(void* const* d_in, const int* in_sizes, int n_in,
                              void* d_out, int out_size, void* d_ws,
                              size_t ws_size, hipStream_t stream) {
  (void)in_sizes; (void)n_in; (void)out_size;
  const float* x    = (const float*)d_in[0];
  // d_in[1] = target_seq_len (=256, shapes are static -> hardcoded)
  const float* Wih  = (const float*)d_in[2];
  const float* Whh  = (const float*)d_in[3];
  const float* bih  = (const float*)d_in[4];
  const float* bhh  = (const float*)d_in[5];
  const float* Wlin = (const float*)d_in[6];
  const float* blin = (const float*)d_in[7];
  float* out = (float*)d_out;

  char* ws = (char*)d_ws;
  unsigned* ctrs = (unsigned*)ws;                 // 2x 1KB barrier lines
  float* h0 = (float*)(ws + WS_H_OFF);            // 512KB
  float* h1 = h0 + (long)B_SZ * H_SZ;             // 512KB
  float* yb = h1 + (long)B_SZ * H_SZ;             // 128KB
  const size_t needed = WS_H_OFF + (size_t)B_SZ * H_SZ * 4 * 2 +
                        (size_t)B_SZ * I_SZ * 4;
  if (ws_size < needed) return;  // output stays poisoned -> visible failure

  // zero barrier counters + h0 (re-poisoned to 0xAA before every timed call)
  hipMemsetAsync(d_ws, 0, WS_H_OFF + (size_t)B_SZ * H_SZ * 4, stream);

  hipFuncSetAttribute(reinterpret_cast<const void*>(gru_ar_kernel),
                      hipFuncAttributeMaxDynamicSharedMemorySize, SMEM_BYTES);

  void* args[] = {&x, &Wih, &Whh, &bih, &bhh, &Wlin, &blin,
                  &out, &h0, &h1, &yb, &ctrs};
  hipError_t e = hipLaunchCooperativeKernel(
      reinterpret_cast<const void*>(gru_ar_kernel), dim3(NWG), dim3(NTHR),
      args, SMEM_BYTES, stream);
  if (e != hipSuccess) {
    // fallback: plain launch (grid == 256 CUs x 1 WG -> co-resident anyway)
    gru_ar_kernel<<<dim3(NWG), dim3(NTHR), SMEM_BYTES, stream>>>(
        x, Wih, Whh, bih, bhh, Wlin, blin, out, h0, h1, yb, ctrs);
  }
}

// Round 5
// 124092.603 us; speedup vs baseline: 1.0056x; 1.0056x over previous
//
#include <hip/hip_runtime.h>

// ============================================================================
// GRU encode (1024 steps) + autoregressive decode (256 steps), B=128, I=256,
// H=1024, fp32 (no fp32 MFMA on CDNA4 — vector-ALU path).
//
// Round-2 fix (still unmeasured due to GPU timeouts; resubmitted verbatim):
// phase loop HAND-UNROLLED with literal phase ids. The rolled `for(p<5)`
// selected accA-vs-accB at runtime -> both accumulator arrays lived in
// scratch (rule #20 signature: VGPR=72, WRITE_SIZE=79GB spill write-backs,
// VALUBusy 25%, 124.8ms). Static accumulator naming keeps them in VGPRs.
// ============================================================================

#define I_SZ 256
#define H_SZ 1024
#define B_SZ 128
#define S_SZ 1024
#define T_SZ 256

#define NWG 256
#define NTHR 512
#define SLOTS 33                      // float4 slots per 128-float row (32+1 pad)
#define BUF_F4 (64 * SLOTS)           // 2112 float4 per chunk buffer
#define SMEM_BYTES (4 * BUF_F4 * 16)  // 135168 bytes (4 chunk buffers)

#define WS_H_OFF 4096

__device__ __forceinline__ float sigmoidf_(float v) {
  return 1.0f / (1.0f + __expf(-v));
}
__device__ __forceinline__ float tanhf_(float v) {
  return 2.0f / (1.0f + __expf(-2.0f * v)) - 1.0f;
}

__global__ void __launch_bounds__(NTHR, 2)
gru_ar_kernel(const float* __restrict__ x, const float* __restrict__ Wih,
              const float* __restrict__ Whh, const float* __restrict__ bih,
              const float* __restrict__ bhh, const float* __restrict__ Wlin,
              const float* __restrict__ blin, float* __restrict__ out,
              float* __restrict__ h0, float* __restrict__ h1,
              float* __restrict__ ybuf, unsigned* __restrict__ ctrs) {
  extern __shared__ float4 smem4[];
  const int tid = threadIdx.x;
  const int wg  = blockIdx.x;
  const int g   = wg >> 7;    // batch group 0/1
  const int wgl = wg & 127;   // WG index within group
  const int u0  = wgl * 8;    // this WG's 8 hidden units
  const int bg0 = g * 64;     // group's first batch
  const int b   = tid & 63;   // thread's batch (lane)
  const int rg  = __builtin_amdgcn_readfirstlane((tid >> 6) & 3);  // row group
  const int kh  = __builtin_amdgcn_readfirstlane(tid >> 8);        // k half
  const int wv  = __builtin_amdgcn_readfirstlane(tid >> 6);        // wave id

  // 6 gate rows: units u0+rg*2 .. +1, gates (r,z,n). Rows: [0:H)=r [H:2H)=z
  // [2H:3H)=n. grow[] is wave-uniform (rg is readfirstlane'd) -> weight loads
  // are uniform-address (scalar-cache eligible).
  int grow[6];
  float bi[6], bh_[6];
#pragma unroll
  for (int jj = 0; jj < 6; ++jj) {
    const int jloc = rg * 6 + jj;
    grow[jj] = (jloc % 3) * H_SZ + u0 + jloc / 3;
    bi[jj]   = bih[grow[jj]];
    bh_[jj]  = bhh[grow[jj]];
  }

  unsigned* myline = ctrs + g * 256 + (wgl & 7) * 32;  // 128B-spaced lines
  float* hc = h0;
  float* hn = h1;
  int phase = 0;

  // group barrier: relaxed spin (no per-iteration L1/L2 invalidate), single
  // fence on each side.
  auto group_barrier = [&]() {
    ++phase;
    __syncthreads();
    if (tid == 0) {
      __threadfence();
      __hip_atomic_fetch_add(myline, 1u, __ATOMIC_RELAXED,
                             __HIP_MEMORY_SCOPE_AGENT);
    }
    if (tid < 8) {
      unsigned* ln = ctrs + g * 256 + tid * 32;
      const unsigned tgt = (unsigned)phase * 16u;  // 16 WGs per line
      while (__hip_atomic_load(ln, __ATOMIC_RELAXED,
                               __HIP_MEMORY_SCOPE_AGENT) < tgt)
        __builtin_amdgcn_s_sleep(2);
      __threadfence();
    }
    __syncthreads();
  };

  // one FMA chunk: 6 rows x 128 k; X from LDS, W uniform from global.
  // ac MUST be a statically named array at every call site (register alloc).
  auto do_chunk = [&](float (&ac)[6], const float4* __restrict__ xb,
                      const float* __restrict__ wbase, long wstride, int kc0) {
    const float* wp[6];
#pragma unroll
    for (int jj = 0; jj < 6; ++jj)
      wp[jj] = wbase + (long)grow[jj] * wstride + kc0;
#pragma unroll 8
    for (int k4 = 0; k4 < 32; ++k4) {
      const float4 xv = xb[k4];
#pragma unroll
      for (int jj = 0; jj < 6; ++jj) {
        const float4 wv4 = *(const float4*)(wp[jj] + 4 * k4);
        ac[jj] = fmaf(xv.x, wv4.x, ac[jj]);
        ac[jj] = fmaf(xv.y, wv4.y, ac[jj]);
        ac[jj] = fmaf(xv.z, wv4.z, ac[jj]);
        ac[jj] = fmaf(xv.w, wv4.w, ac[jj]);
      }
    }
  };

  // one GRU gate step: X = concat(srcA row [0:256), h [256:1280))
  auto gates_step = [&](const float* srcA, long strA) {
    float accA[6], accB[6];
#pragma unroll
    for (int i = 0; i < 6; ++i) { accA[i] = 0.f; accB[i] = 0.f; }
    const float* hg = hc + (long)bg0 * H_SZ;

    const int srow = tid >> 3;       // staging row 0..63
    const int s0   = (tid & 7) * 4;  // staging f4 slot base
    float4 pf[8];

    // pair is ALWAYS a literal at call sites -> kc folds, branch resolves.
    auto stage_issue = [&](int pair) {
#pragma unroll
      for (int h = 0; h < 2; ++h) {
        const int kc = h * 640 + pair * 128;  // never straddles k=256
        const float* src; long rs;
        if (kc < 256) { src = srcA + kc;         rs = strA; }
        else          { src = hg + (kc - 256);   rs = H_SZ; }
        const float* p = src + (long)srow * rs + 4 * s0;
#pragma unroll
        for (int i = 0; i < 4; ++i)
          pf[h * 4 + i] = *(const float4*)(p + 4 * i);
      }
    };
    auto stage_write = [&](int pair) {
#pragma unroll
      for (int h = 0; h < 2; ++h) {
        float4* bufb = smem4 + (h * 2 + (pair & 1)) * BUF_F4;
#pragma unroll
        for (int i = 0; i < 4; ++i)
          bufb[srow * SLOTS + s0 + i] = pf[h * 4 + i];
      }
    };
    // compute-phase LDS base for (my kh, phase p) — p literal at call sites
    auto XB = [&](int p) -> const float4* {
      return smem4 + (kh * 2 + (p & 1)) * BUF_F4 + b * SLOTS;
    };

    stage_issue(0);
    stage_write(0);
    __syncthreads();

    // ---- phase 0 (kh=0: x k[0:128) -> accA ; kh=1: h k[384:512) -> accB)
    stage_issue(1);
    if (kh == 0) do_chunk(accA, XB(0), Wih, I_SZ, 0);
    else         do_chunk(accB, XB(0), Whh, H_SZ, 384);
    stage_write(1);
    __syncthreads();
    // ---- phase 1
    stage_issue(2);
    if (kh == 0) do_chunk(accA, XB(1), Wih, I_SZ, 128);
    else         do_chunk(accB, XB(1), Whh, H_SZ, 512);
    stage_write(2);
    __syncthreads();
    // ---- phase 2
    stage_issue(3);
    if (kh == 0) do_chunk(accB, XB(2), Whh, H_SZ, 0);
    else         do_chunk(accB, XB(2), Whh, H_SZ, 640);
    stage_write(3);
    __syncthreads();
    // ---- phase 3
    stage_issue(4);
    if (kh == 0) do_chunk(accB, XB(3), Whh, H_SZ, 128);
    else         do_chunk(accB, XB(3), Whh, H_SZ, 768);
    stage_write(4);
    __syncthreads();
    // ---- phase 4
    if (kh == 0) do_chunk(accB, XB(4), Whh, H_SZ, 256);
    else         do_chunk(accB, XB(4), Whh, H_SZ, 896);
    __syncthreads();

    // fold k-half 1's h-part partials into k-half 0
    float* red = (float*)smem4;  // reuse buffer 0 region (sync'd above)
    if (kh == 1) {
#pragma unroll
      for (int jj = 0; jj < 6; ++jj) red[(tid & 255) * 6 + jj] = accB[jj];
    }
    __syncthreads();
    if (kh == 0) {
#pragma unroll
      for (int jj = 0; jj < 6; ++jj) accB[jj] += red[tid * 6 + jj];
#pragma unroll
      for (int ui = 0; ui < 2; ++ui) {
        const int j0 = ui * 3;
        const float rr = sigmoidf_(accA[j0]     + accB[j0]     + bi[j0]     + bh_[j0]);
        const float zz = sigmoidf_(accA[j0 + 1] + accB[j0 + 1] + bi[j0 + 1] + bh_[j0 + 1]);
        const float nn = tanhf_(accA[j0 + 2] + bi[j0 + 2] +
                                rr * (accB[j0 + 2] + bh_[j0 + 2]));
        const int u = u0 + rg * 2 + ui;
        const long hidx = (long)(bg0 + b) * H_SZ + u;
        const float hp = hc[hidx];
        hn[hidx] = (1.f - zz) * nn + zz * hp;
      }
    }
  };

  // y = h @ Wlin^T + blin  (2 output cols per WG, 4-way K split)
  auto lin_step = [&](bool emit, int tstep) {
    const float* hg = hc + (long)bg0 * H_SZ;
    const int o0 = wgl * 2;
    const int o_loc = wv & 1;
    const int sec   = wv >> 1;  // k section 0..3
    float accl = 0.f;
#pragma unroll
    for (int r = 0; r < 2; ++r) {
#pragma unroll
      for (int i = 0; i < 16; ++i) {
        const int f = tid + i * 512;                // 8192 f4 = 4 chunks
        const int bq = f >> 11, rem = f & 2047;
        const int row = rem >> 5, slot = rem & 31;
        const int k = bq * 256 + r * 128 + slot * 4;
        smem4[bq * BUF_F4 + row * SLOTS + slot] =
            *(const float4*)(hg + (long)row * H_SZ + k);
      }
      __syncthreads();
      const float4* xb = smem4 + sec * BUF_F4 + b * SLOTS;
      const float* wl = Wlin + (long)(o0 + o_loc) * H_SZ + sec * 256 + r * 128;
#pragma unroll 8
      for (int k4 = 0; k4 < 32; ++k4) {
        const float4 xv = xb[k4];
        const float4 wv4 = *(const float4*)(wl + 4 * k4);
        accl = fmaf(xv.x, wv4.x, accl);
        accl = fmaf(xv.y, wv4.y, accl);
        accl = fmaf(xv.z, wv4.z, accl);
        accl = fmaf(xv.w, wv4.w, accl);
      }
      __syncthreads();
    }
    float* red = (float*)smem4;
    red[(o_loc * 64 + b) * 4 + sec] = accl;
    __syncthreads();
    if (tid < 128) {
      const int bb = tid & 63, ol = tid >> 6;
      const float y = red[tid * 4 + 0] + red[tid * 4 + 1] +
                      red[tid * 4 + 2] + red[tid * 4 + 3] + blin[o0 + ol];
      ybuf[(long)(bg0 + bb) * I_SZ + o0 + ol] = y;
      if (emit)
        out[((long)(bg0 + bb) * T_SZ + tstep) * I_SZ + o0 + ol] = y;
    }
  };

  // ======================= encode =======================
  for (int t = 0; t < S_SZ; ++t) {
    gates_step(x + ((long)bg0 * S_SZ + t) * I_SZ, (long)S_SZ * I_SZ);
    group_barrier();
    float* tmp = hc; hc = hn; hn = tmp;
  }
  // ======================= y0 ===========================
  lin_step(false, 0);
  group_barrier();
  // ======================= decode =======================
  for (int t = 0; t < T_SZ; ++t) {
    gates_step(ybuf + (long)bg0 * I_SZ, I_SZ);
    group_barrier();
    float* tmp = hc; hc = hn; hn = tmp;
    lin_step(true, t);
    group_barrier();
  }
}

extern "C" void kernel_launch(void* const* d_in, const int* in_sizes, int n_in,
                              void* d_out, int out_size, void* d_ws,
                              size_t ws_size, hipStream_t stream) {
  (void)in_sizes; (void)n_in; (void)out_size;
  const float* x    = (const float*)d_in[0];
  // d_in[1] = target_seq_len (=256, static shapes -> hardcoded)
  const float* Wih  = (const float*)d_in[2];
  const float* Whh  = (const float*)d_in[3];
  const float* bih  = (const float*)d_in[4];
  const float* bhh  = (const float*)d_in[5];
  const float* Wlin = (const float*)d_in[6];
  const float* blin = (const float*)d_in[7];
  float* out = (float*)d_out;

  char* ws = (char*)d_ws;
  unsigned* ctrs = (unsigned*)ws;                 // 2x 1KB barrier lines
  float* h0 = (float*)(ws + WS_H_OFF);            // 512KB
  float* h1 = h0 + (long)B_SZ * H_SZ;             // 512KB
  float* yb = h1 + (long)B_SZ * H_SZ;             // 128KB
  const size_t needed = WS_H_OFF + (size_t)B_SZ * H_SZ * 4 * 2 +
                        (size_t)B_SZ * I_SZ * 4;
  if (ws_size < needed) return;

  hipMemsetAsync(d_ws, 0, WS_H_OFF + (size_t)B_SZ * H_SZ * 4, stream);

  hipFuncSetAttribute(reinterpret_cast<const void*>(gru_ar_kernel),
                      hipFuncAttributeMaxDynamicSharedMemorySize, SMEM_BYTES);

  void* args[] = {&x, &Wih, &Whh, &bih, &bhh, &Wlin, &blin,
                  &out, &h0, &h1, &yb, &ctrs};
  hipError_t e = hipLaunchCooperativeKernel(
      reinterpret_cast<const void*>(gru_ar_kernel), dim3(NWG), dim3(NTHR),
      args, SMEM_BYTES, stream);
  if (e != hipSuccess) {
    gru_ar_kernel<<<dim3(NWG), dim3(NTHR), SMEM_BYTES, stream>>>(
        x, Wih, Whh, bih, bhh, Wlin, blin, out, h0, h1, yb, ctrs);
  }
}

// Round 6
// 87507.697 us; speedup vs baseline: 1.4260x; 1.4181x over previous
//
#include <hip/hip_runtime.h>

// ============================================================================
// GRU encode (1024) + AR decode (256), B=128, I=256, H=1024, fp32 vector path.
//
// Round-5: X staging rewritten to __builtin_amdgcn_global_load_lds (16B DMA).
// Evidence: hand-unroll produced IDENTICAL counters (VGPR=72, WRITE=75GB,
// VALUBusy 24%) -> compiler had already unrolled; the scratch flood is the
// pf[8] global->reg->LDS round-trip being spilled. DMA staging removes those
// registers entirely, removes ds_writes, and overlaps HBM/L2 latency with the
// chunk compute. Linear LDS dest forces an XOR swizzle, applied BOTH sides
// (pre-swizzled global source + swizzled read; rule #21): phys_slot =
// log_slot ^ (row&31) -> X reads are 2-way bank-aliased (free).
// ============================================================================

#define I_SZ 256
#define H_SZ 1024
#define B_SZ 128
#define S_SZ 1024
#define T_SZ 256

#define NWG 256
#define NTHR 512
#define BUF_F4 2048                    // 64 rows x 32 float4 (128 k), linear
#define SMEM_BYTES (4 * BUF_F4 * 16)   // 131072 B = 4 chunk buffers

#define WS_H_OFF 4096

__device__ __forceinline__ float sigmoidf_(float v) {
  return 1.0f / (1.0f + __expf(-v));
}
__device__ __forceinline__ float tanhf_(float v) {
  return 2.0f / (1.0f + __expf(-2.0f * v)) - 1.0f;
}

// 16B global -> LDS DMA. LDS dest is wave-uniform base + lane*16.
__device__ __forceinline__ void dma16(const float* g, void* l) {
  __builtin_amdgcn_global_load_lds(
      (const __attribute__((address_space(1))) void*)g,
      (__attribute__((address_space(3))) void*)l, 16, 0, 0);
}

__global__ void __launch_bounds__(NTHR, 2)
gru_ar_kernel(const float* __restrict__ x, const float* __restrict__ Wih,
              const float* __restrict__ Whh, const float* __restrict__ bih,
              const float* __restrict__ bhh, const float* __restrict__ Wlin,
              const float* __restrict__ blin, float* __restrict__ out,
              float* __restrict__ h0, float* __restrict__ h1,
              float* __restrict__ ybuf, unsigned* __restrict__ ctrs) {
  extern __shared__ float4 smem4[];
  const int tid  = threadIdx.x;
  const int wg   = blockIdx.x;
  const int g    = wg >> 7;    // batch group 0/1
  const int wgl  = wg & 127;   // WG index within group
  const int u0   = wgl * 8;    // this WG's 8 hidden units
  const int bg0  = g * 64;     // group's first batch
  const int b    = tid & 63;   // thread's batch (lane)
  const int lane = tid & 63;
  const int rg   = __builtin_amdgcn_readfirstlane((tid >> 6) & 3);  // row group
  const int kh   = __builtin_amdgcn_readfirstlane(tid >> 8);        // k half
  const int wv   = __builtin_amdgcn_readfirstlane(tid >> 6);        // wave id

  // 6 gate rows: units u0+rg*2, +1; gates (r,z,n). Rows: [0:H)=r [H:2H)=z
  // [2H:3H)=n. grow[] wave-uniform -> weight loads are uniform-address.
  int grow[6];
  float bi[6], bh_[6];
#pragma unroll
  for (int jj = 0; jj < 6; ++jj) {
    const int jloc = rg * 6 + jj;
    grow[jj] = (jloc % 3) * H_SZ + u0 + jloc / 3;
    bi[jj]   = bih[grow[jj]];
    bh_[jj]  = bhh[grow[jj]];
  }

  unsigned* myline = ctrs + g * 256 + (wgl & 7) * 32;  // 128B-spaced lines
  float* hc = h0;
  float* hn = h1;
  int phase = 0;

  // group barrier: relaxed spin + one fence per side (no per-iter invalidate)
  auto group_barrier = [&]() {
    ++phase;
    __syncthreads();
    if (tid == 0) {
      __threadfence();
      __hip_atomic_fetch_add(myline, 1u, __ATOMIC_RELAXED,
                             __HIP_MEMORY_SCOPE_AGENT);
    }
    if (tid < 8) {
      unsigned* ln = ctrs + g * 256 + tid * 32;
      const unsigned tgt = (unsigned)phase * 16u;  // 16 WGs per line
      while (__hip_atomic_load(ln, __ATOMIC_RELAXED,
                               __HIP_MEMORY_SCOPE_AGENT) < tgt)
        __builtin_amdgcn_s_sleep(2);
      __threadfence();
    }
    __syncthreads();
  };

  // one FMA chunk: 6 rows x 128 k; X from LDS (XOR-swizzled), W uniform global
  auto do_chunk = [&](float (&ac)[6], const float4* __restrict__ xbuf,
                      const float* __restrict__ wbase, long wstride, int kc0) {
    const float* wp[6];
#pragma unroll
    for (int jj = 0; jj < 6; ++jj)
      wp[jj] = wbase + (long)grow[jj] * wstride + kc0;
    const float4* xrow = xbuf + b * 32;
    const int bs = b & 31;
#pragma unroll 8
    for (int k4 = 0; k4 < 32; ++k4) {
      const float4 xv = xrow[k4 ^ bs];  // read-side swizzle (matches source)
#pragma unroll
      for (int jj = 0; jj < 6; ++jj) {
        const float4 wv4 = *(const float4*)(wp[jj] + 4 * k4);
        ac[jj] = fmaf(xv.x, wv4.x, ac[jj]);
        ac[jj] = fmaf(xv.y, wv4.y, ac[jj]);
        ac[jj] = fmaf(xv.z, wv4.z, ac[jj]);
        ac[jj] = fmaf(xv.w, wv4.w, ac[jj]);
      }
    }
  };

  // one GRU gate step: X = concat(srcA row [0:256), h [256:1280))
  auto gates_step = [&](const float* srcA, long strA) {
    float accA[6], accB[6];
#pragma unroll
    for (int i = 0; i < 6; ++i) { accA[i] = 0.f; accB[i] = 0.f; }
    const float* hg = hc + (long)bg0 * H_SZ;

    // stage chunk pair (kh0: kc=pair*128, kh1: kc=640+pair*128) via DMA.
    // Linear LDS slot idx -> row bb=idx>>5, phys slot sp=idx&31; the global
    // SOURCE supplies logical slot sl = sp ^ (bb&31)  (both-sides swizzle).
    auto stage_pair = [&](int pair) {
#pragma unroll
      for (int hh = 0; hh < 2; ++hh) {
        const int kc = hh * 640 + pair * 128;  // never straddles k=256
        const float* base; long rs; int koff;
        if (kc < 256) { base = srcA; rs = strA;  koff = kc; }
        else          { base = hg;   rs = H_SZ;  koff = kc - 256; }
        char* bufb = (char*)(smem4 + (hh * 2 + (pair & 1)) * BUF_F4);
#pragma unroll
        for (int j = 0; j < 4; ++j) {
          const int idx = wv * 256 + j * 64 + lane;
          const int bb  = idx >> 5;
          const int sl  = (idx & 31) ^ (bb & 31);
          const float* src = base + (long)bb * rs + koff + sl * 4;
          dma16(src, bufb + (wv * 256 + j * 64) * 16);
        }
      }
    };
    auto XB = [&](int p) -> const float4* {
      return smem4 + (kh * 2 + (p & 1)) * BUF_F4;
    };

    // prologue: stage pair 0, drain, sync
    stage_pair(0);
    asm volatile("s_waitcnt vmcnt(0)" ::: "memory");
    __syncthreads();

    // phase 0: issue next DMA, compute current (DMA overlaps compute)
    stage_pair(1);
    if (kh == 0) do_chunk(accA, XB(0), Wih, I_SZ, 0);
    else         do_chunk(accB, XB(0), Whh, H_SZ, 384);
    asm volatile("s_waitcnt vmcnt(0)" ::: "memory");
    __syncthreads();
    // phase 1
    stage_pair(2);
    if (kh == 0) do_chunk(accA, XB(1), Wih, I_SZ, 128);
    else         do_chunk(accB, XB(1), Whh, H_SZ, 512);
    asm volatile("s_waitcnt vmcnt(0)" ::: "memory");
    __syncthreads();
    // phase 2
    stage_pair(3);
    if (kh == 0) do_chunk(accB, XB(2), Whh, H_SZ, 0);
    else         do_chunk(accB, XB(2), Whh, H_SZ, 640);
    asm volatile("s_waitcnt vmcnt(0)" ::: "memory");
    __syncthreads();
    // phase 3
    stage_pair(4);
    if (kh == 0) do_chunk(accB, XB(3), Whh, H_SZ, 128);
    else         do_chunk(accB, XB(3), Whh, H_SZ, 768);
    asm volatile("s_waitcnt vmcnt(0)" ::: "memory");
    __syncthreads();
    // phase 4
    if (kh == 0) do_chunk(accB, XB(4), Whh, H_SZ, 256);
    else         do_chunk(accB, XB(4), Whh, H_SZ, 896);
    __syncthreads();

    // fold k-half 1's h-part partials into k-half 0
    float* red = (float*)smem4;  // reuse buffer A0 region (sync'd above)
    if (kh == 1) {
#pragma unroll
      for (int jj = 0; jj < 6; ++jj) red[(tid & 255) * 6 + jj] = accB[jj];
    }
    __syncthreads();
    if (kh == 0) {
#pragma unroll
      for (int jj = 0; jj < 6; ++jj) accB[jj] += red[tid * 6 + jj];
#pragma unroll
      for (int ui = 0; ui < 2; ++ui) {
        const int j0 = ui * 3;
        const float rr = sigmoidf_(accA[j0]     + accB[j0]     + bi[j0]     + bh_[j0]);
        const float zz = sigmoidf_(accA[j0 + 1] + accB[j0 + 1] + bi[j0 + 1] + bh_[j0 + 1]);
        const float nn = tanhf_(accA[j0 + 2] + bi[j0 + 2] +
                                rr * (accB[j0 + 2] + bh_[j0 + 2]));
        const int u = u0 + rg * 2 + ui;
        const long hidx = (long)(bg0 + b) * H_SZ + u;
        const float hp = hc[hidx];
        hn[hidx] = (1.f - zz) * nn + zz * hp;
      }
    }
  };

  // y = h @ Wlin^T + blin  (2 output cols per WG, 4-way K split)
  auto lin_step = [&](bool emit, int tstep) {
    const float* hg = hc + (long)bg0 * H_SZ;
    const int o0 = wgl * 2;
    const int o_loc = wv & 1;
    const int sec   = wv >> 1;  // k section 0..3
    float accl = 0.f;
#pragma unroll
    for (int r = 0; r < 2; ++r) {
      // stage 4 chunks (sections) of h: [64 rows][32 f4] each, via DMA
#pragma unroll
      for (int bq = 0; bq < 4; ++bq) {
        char* bufb = (char*)(smem4 + bq * BUF_F4);
#pragma unroll
        for (int j = 0; j < 4; ++j) {
          const int idx = wv * 256 + j * 64 + lane;
          const int bb  = idx >> 5;
          const int sl  = (idx & 31) ^ (bb & 31);
          const float* src = hg + (long)bb * H_SZ + bq * 256 + r * 128 + sl * 4;
          dma16(src, bufb + (wv * 256 + j * 64) * 16);
        }
      }
      asm volatile("s_waitcnt vmcnt(0)" ::: "memory");
      __syncthreads();
      const float4* xsec = smem4 + sec * BUF_F4 + b * 32;
      const int bs = b & 31;
      const float* wl = Wlin + (long)(o0 + o_loc) * H_SZ + sec * 256 + r * 128;
#pragma unroll 8
      for (int k4 = 0; k4 < 32; ++k4) {
        const float4 xv = xsec[k4 ^ bs];
        const float4 wv4 = *(const float4*)(wl + 4 * k4);
        accl = fmaf(xv.x, wv4.x, accl);
        accl = fmaf(xv.y, wv4.y, accl);
        accl = fmaf(xv.z, wv4.z, accl);
        accl = fmaf(xv.w, wv4.w, accl);
      }
      __syncthreads();
    }
    float* red = (float*)smem4;
    red[(o_loc * 64 + b) * 4 + sec] = accl;
    __syncthreads();
    if (tid < 128) {
      const int bb = tid & 63, ol = tid >> 6;
      const float y = red[tid * 4 + 0] + red[tid * 4 + 1] +
                      red[tid * 4 + 2] + red[tid * 4 + 3] + blin[o0 + ol];
      ybuf[(long)(bg0 + bb) * I_SZ + o0 + ol] = y;
      if (emit)
        out[((long)(bg0 + bb) * T_SZ + tstep) * I_SZ + o0 + ol] = y;
    }
  };

  // ======================= encode =======================
  for (int t = 0; t < S_SZ; ++t) {
    gates_step(x + ((long)bg0 * S_SZ + t) * I_SZ, (long)S_SZ * I_SZ);
    group_barrier();
    float* tmp = hc; hc = hn; hn = tmp;
  }
  // ======================= y0 ===========================
  lin_step(false, 0);
  group_barrier();
  // ======================= decode =======================
  for (int t = 0; t < T_SZ; ++t) {
    gates_step(ybuf + (long)bg0 * I_SZ, I_SZ);
    group_barrier();
    float* tmp = hc; hc = hn; hn = tmp;
    lin_step(true, t);
    group_barrier();
  }
}

extern "C" void kernel_launch(void* const* d_in, const int* in_sizes, int n_in,
                              void* d_out, int out_size, void* d_ws,
                              size_t ws_size, hipStream_t stream) {
  (void)in_sizes; (void)n_in; (void)out_size;
  const float* x    = (const float*)d_in[0];
  // d_in[1] = target_seq_len (=256, static shapes -> hardcoded)
  const float* Wih  = (const float*)d_in[2];
  const float* Whh  = (const float*)d_in[3];
  const float* bih  = (const float*)d_in[4];
  const float* bhh  = (const float*)d_in[5];
  const float* Wlin = (const float*)d_in[6];
  const float* blin = (const float*)d_in[7];
  float* out = (float*)d_out;

  char* ws = (char*)d_ws;
  unsigned* ctrs = (unsigned*)ws;                 // 2x 1KB barrier lines
  float* h0 = (float*)(ws + WS_H_OFF);            // 512KB
  float* h1 = h0 + (long)B_SZ * H_SZ;             // 512KB
  float* yb = h1 + (long)B_SZ * H_SZ;             // 128KB
  const size_t needed = WS_H_OFF + (size_t)B_SZ * H_SZ * 4 * 2 +
                        (size_t)B_SZ * I_SZ * 4;
  if (ws_size < needed) return;

  hipMemsetAsync(d_ws, 0, WS_H_OFF + (size_t)B_SZ * H_SZ * 4, stream);

  hipFuncSetAttribute(reinterpret_cast<const void*>(gru_ar_kernel),
                      hipFuncAttributeMaxDynamicSharedMemorySize, SMEM_BYTES);

  void* args[] = {&x, &Wih, &Whh, &bih, &bhh, &Wlin, &blin,
                  &out, &h0, &h1, &yb, &ctrs};
  hipError_t e = hipLaunchCooperativeKernel(
      reinterpret_cast<const void*>(gru_ar_kernel), dim3(NWG), dim3(NTHR),
      args, SMEM_BYTES, stream);
  if (e != hipSuccess) {
    gru_ar_kernel<<<dim3(NWG), dim3(NTHR), SMEM_BYTES, stream>>>(
        x, Wih, Whh, bih, bhh, Wlin, blin, out, h0, h1, yb, ctrs);
  }
}